// Round 11
// baseline (99.244 us; speedup 1.0000x reference)
//
#include <hip/hip_runtime.h>
#include <hip/hip_bf16.h>

#define B_ROWS 4096
#define TWOB   8192
#define DIM    256
#define INV_T  14.285714285714286f  // 1/0.07
#define EXP2C  20.609928930611884f  // INV_T * log2(e): exp(s/T) = exp2(s*EXP2C)

#define BM 128
#define BN 128
#define NQ 8              // col-chunk blocks per row tile (4 tiles each, q==7&&rt<32 has 5)
// strip_sums sub-slots (one producer wave each -> plain stores, no atomics/zero-init):
//   0..63  : col-sum slot (jdist-1)*2 + wr, jdist = 1..32
//   64..79 : row-sum slot 64 + q*2 + wc
#define NSLOT 80

typedef __bf16 bf16x8 __attribute__((ext_vector_type(8)));
typedef float  f32x4  __attribute__((ext_vector_type(4)));

// ---------------- kernel 1: row L2-normalize, fp32 -> bf16 ----------------
// Also zeroes the finalize accumulators (ws is re-poisoned 0xAA before every launch).
__global__ __launch_bounds__(256) void normalize_k(const float* __restrict__ zi,
                                                   const float* __restrict__ zj,
                                                   unsigned short* __restrict__ zn,
                                                   float* __restrict__ loss_acc,
                                                   unsigned int* __restrict__ counter) {
    if (blockIdx.x == 0 && threadIdx.x == 0) {
        loss_acc[0] = 0.0f;
        counter[0]  = 0u;
    }
    int wave = threadIdx.x >> 6;
    int lane = threadIdx.x & 63;
    int row  = blockIdx.x * 4 + wave;             // 2048 blocks * 4 waves = 8192 rows
    const float* src = (row < B_ROWS) ? (zi + (size_t)row * DIM)
                                      : (zj + (size_t)(row - B_ROWS) * DIM);
    float4 v = reinterpret_cast<const float4*>(src)[lane];   // 64 lanes * 4 = 256
    float ss = v.x * v.x + v.y * v.y + v.z * v.z + v.w * v.w;
#pragma unroll
    for (int off = 32; off >= 1; off >>= 1) ss += __shfl_xor(ss, off);
    float norm = sqrtf(ss);
    norm = fmaxf(norm, 1e-8f);                    // COS_EPS
    float inv = 1.0f / norm;
    ushort4 o;
    o.x = __builtin_bit_cast(unsigned short, __float2bfloat16(v.x * inv));
    o.y = __builtin_bit_cast(unsigned short, __float2bfloat16(v.y * inv));
    o.z = __builtin_bit_cast(unsigned short, __float2bfloat16(v.z * inv));
    o.w = __builtin_bit_cast(unsigned short, __float2bfloat16(v.w * inv));
    reinterpret_cast<ushort4*>(zn)[(size_t)row * 64 + lane] = o;
}

// ---------------- kernel 2: symmetric flash NT-Xent main ----------------
// sim = zn@zn^T is SYMMETRIC: each off-diagonal tile (r,c) supplies row sums for
// rows of r (rsum regs) AND, via its col sums, row sums for rows of c. Upper band
// only: block (rt,q) handles col tiles c=(rt+j)&63, j in {4q..4q+3} (+ j=32 for
// q==7, rt<32) -> 2080 of 4096 tiles. Compute loop = R0's verified structure
// (A LDS-resident staged once, B ping-pong staged one kstep ahead, 80 KB LDS,
// LDS-bound 2 blocks/CU). R11 (= R10 with the correct builtin): epilogue trims —
// (1) exp2-fold: exp(s/T) = exp2(s*EXP2C) via __builtin_amdgcn_exp2f (v_exp_f32
// computes 2^x natively; deletes the separate INV_T mul per element);
// (2) pos captures RAW sim, scaled once at the deferred store; (3) cadd
// accumulation skipped on diag tiles (wave-uniform branch).
__global__ __launch_bounds__(256, 2) void ntxent_main(const unsigned short* __restrict__ znu,
                                                      float* __restrict__ pos,
                                                      float* __restrict__ strip_sums) {
    const __bf16* zn = (const __bf16*)znu;
    __shared__ __attribute__((aligned(16))) __bf16 As[8][BM * 32];   // 8 kt-chunks x 8 KB = 64 KB
    __shared__ __attribute__((aligned(16))) __bf16 Bs[2][BN * 32];   // ping-pong, 16 KB

    const int tid  = threadIdx.x;
    const int wave = tid >> 6;
    const int lane = tid & 63;
    const int wr = wave >> 1, wc = wave & 1;
    const int quad = lane >> 4, lc = lane & 15;
    const int rt = blockIdx.x;           // row-tile 0..63
    const int q  = blockIdx.y;           // col-chunk 0..7
    const int q4 = q * 4;
    const int row0 = rt * BM;
    const int NCT = (q == 7 && rt < 32) ? 5 : 4;
#define COLOF(i) ((rt + (((i) == 4) ? 32 : (q4 + (i)))) & 63)

    // staging: per-lane global element offsets for this wave's two 1KB chunks per stage.
    // chunk c = j*64+lane -> (m=c>>2, kc_lds=c&3); source kc_g = kc_lds ^ sw(m)  (involution)
    int stg_off[2];
#pragma unroll
    for (int t = 0; t < 2; ++t) {
        int c  = (wave * 2 + t) * 64 + lane;
        int m  = c >> 2;
        int kc = (c & 3) ^ ((m & 3) ^ ((m >> 2) & 3));
        stg_off[t] = m * DIM + kc * 8;
    }

    // fragment-read byte offsets within one 8KB chunk (swizzle depends only on m&15 == lc)
    const int sw    = (lc & 3) ^ ((lc >> 2) & 3);
    const int aBase = (wr * 64 + lc) * 64 + ((quad ^ sw) * 16);
    const int bBase = (wc * 64 + lc) * 64 + ((quad ^ sw) * 16);

    // ---- prologue: stage full A (8 chunks) + first B chunk ----
#pragma unroll
    for (int kt = 0; kt < 8; ++kt) {
#pragma unroll
        for (int t = 0; t < 2; ++t) {
            const int j = wave * 2 + t;
            const __bf16* ga = zn + row0 * DIM + kt * 32 + stg_off[t];
            __builtin_amdgcn_global_load_lds(
                (const __attribute__((address_space(1))) void*)ga,
                (__attribute__((address_space(3))) void*)((char*)As + kt * 8192 + j * 1024), 16, 0, 0);
        }
    }
    {
        const int col0 = COLOF(0) * BN;
#pragma unroll
        for (int t = 0; t < 2; ++t) {
            const int j = wave * 2 + t;
            const __bf16* gb = zn + col0 * DIM + stg_off[t];
            __builtin_amdgcn_global_load_lds(
                (const __attribute__((address_space(1))) void*)gb,
                (__attribute__((address_space(3))) void*)((char*)Bs + j * 1024), 16, 0, 0);
        }
    }

    f32x4 acc[4][4];
    float rsum[4][4];
    float posv[4] = {0.f, 0.f, 0.f, 0.f};
    int   posm[4] = {-1, -1, -1, -1};
#pragma unroll
    for (int mi = 0; mi < 4; ++mi)
#pragma unroll
        for (int r = 0; r < 4; ++r) rsum[mi][r] = 0.0f;

    for (int ct = 0; ct < NCT; ++ct) {
        const int jdist = (ct == 4) ? 32 : (q4 + ct);
        const int c     = (rt + jdist) & 63;
        const int col0  = c * BN;
#pragma unroll
        for (int mi = 0; mi < 4; ++mi)
#pragma unroll
            for (int ni = 0; ni < 4; ++ni) acc[mi][ni] = f32x4{0.f, 0.f, 0.f, 0.f};

#pragma unroll
        for (int kt = 0; kt < 8; ++kt) {
            // barrier: (a) drains the B stage issued one iteration ago (covered
            // by that iteration's compute), (b) guards reuse of Bs[kt+1 & 1].
            __syncthreads();

            // stage next B chunk into the other buffer
            {
                const int nct = (kt == 7) ? ct + 1 : ct;
                const int nkt = (kt + 1) & 7;
                if (nct < NCT) {
                    const int ncol0 = COLOF(nct) * BN;
#pragma unroll
                    for (int t = 0; t < 2; ++t) {
                        const int j = wave * 2 + t;
                        const __bf16* gb = zn + ncol0 * DIM + nkt * 32 + stg_off[t];
                        __builtin_amdgcn_global_load_lds(
                            (const __attribute__((address_space(1))) void*)gb,
                            (__attribute__((address_space(3))) void*)((char*)Bs + ((kt + 1) & 1) * 8192 + j * 1024),
                            16, 0, 0);
                    }
                }
            }

            bf16x8 af[4], bfr[4];
#pragma unroll
            for (int mi = 0; mi < 4; ++mi)
                af[mi] = *(const bf16x8*)((const char*)As + kt * 8192 + aBase + mi * 1024);
#pragma unroll
            for (int ni = 0; ni < 4; ++ni)
                bfr[ni] = *(const bf16x8*)((const char*)Bs + (kt & 1) * 8192 + bBase + ni * 1024);
#pragma unroll
            for (int mi = 0; mi < 4; ++mi)
#pragma unroll
                for (int ni = 0; ni < 4; ++ni)
                    acc[mi][ni] = __builtin_amdgcn_mfma_f32_16x16x32_bf16(
                        af[mi], bfr[ni], acc[mi][ni], 0, 0, 0);
        }

        // epilogue: exp2-folded exp + row sums (C/D: row = quad*4+reg, col = lc)
        // + col sums. Runs while the next tile's kt=0 B stage is in flight.
        const bool isDiag = (jdist == 0);
        const bool isPos  = (jdist == 32);
        float cadd[4] = {0.f, 0.f, 0.f, 0.f};
#pragma unroll
        for (int mi = 0; mi < 4; ++mi) {
#pragma unroll
            for (int ni = 0; ni < 4; ++ni) {
                f32x4 a = acc[mi][ni];
#pragma unroll
                for (int r = 0; r < 4; ++r) {
                    float e = __builtin_amdgcn_exp2f(a[r] * EXP2C);   // = exp(a*INV_T)
                    if (isDiag || isPos) {
                        int gr = row0 + wr * 64 + mi * 16 + quad * 4 + r;
                        int gc = col0 + wc * 64 + ni * 16 + lc;
                        if (isPos && gc == gr + B_ROWS) { posv[mi] = a[r]; posm[mi] = gr; }
                        if (isDiag && gr == gc) e = 0.0f;    // diagonal mask
                    }
                    rsum[mi][r] += e;
                    if (!isDiag) cadd[ni] += e;   // diag tile never flushes cadd
                }
            }
        }

        // col-sum flush: quad reduce (rows within wave) then DIRECT store to the
        // per-wave sub-slot (unique producer -> no atomics, no barrier, no LDS).
        if (!isDiag) {
#pragma unroll
            for (int ni = 0; ni < 4; ++ni) {
                cadd[ni] += __shfl_xor(cadd[ni], 16);   // sum over quad bit 0
                cadd[ni] += __shfl_xor(cadd[ni], 32);   // sum over quad bit 1
            }
            if (quad == 0) {
                float* dst = strip_sums + (size_t)((jdist - 1) * 2 + wr) * TWOB + col0 + wc * 64 + lc;
#pragma unroll
                for (int ni = 0; ni < 4; ++ni) dst[ni * 16] = cadd[ni];
            }
        }
    }

    // deferred pos stores: j==32 tiles hold both directions of each positive pair.
    // posv holds RAW sim; scale by INV_T once here (reference stores logit).
#pragma unroll
    for (int mi = 0; mi < 4; ++mi)
        if (posm[mi] >= 0) {
            float lg = posv[mi] * INV_T;
            pos[posm[mi]] = lg;
            pos[posm[mi] + B_ROWS] = lg;
        }

    // row-sum flush: lane reduce over lc bits then DIRECT store to per-wave sub-slot.
    {
        float* rdst = strip_sums + (size_t)(64 + q * 2 + wc) * TWOB + row0 + wr * 64;
#pragma unroll
        for (int mi = 0; mi < 4; ++mi) {
#pragma unroll
            for (int r = 0; r < 4; ++r) {
                float v = rsum[mi][r];
                v += __shfl_xor(v, 1);
                v += __shfl_xor(v, 2);
                v += __shfl_xor(v, 4);
                v += __shfl_xor(v, 8);
                if (lc == 0) rdst[mi * 16 + quad * 4 + r] = v;
            }
        }
    }
}

// ---------------- kernel 3: loss = mean(log(sumexp) - pos) ----------------
// Row r coverage: col sub-slots 0..61 (j=1..31, both wr) for all rows; 62,63
// (j=32) only for rows >= 4096 (rows < 4096 get distance-32 via row-sum path);
// row sub-slots 64..79. Exactly the 64 tile-distances once each.
__global__ __launch_bounds__(256) void finalize_k(const float* __restrict__ strip_sums,
                                                  const float* __restrict__ pos,
                                                  float* __restrict__ loss_acc,
                                                  unsigned int* __restrict__ counter,
                                                  float* __restrict__ out) {
    __shared__ float wsums[4];
    const int tid = threadIdx.x;
    const int r   = blockIdx.x * 256 + tid;
    float s = 0.0f;
#pragma unroll
    for (int t = 0; t < 62; ++t) s += strip_sums[(size_t)t * TWOB + r];
    if (r >= B_ROWS) {
        s += strip_sums[(size_t)62 * TWOB + r];
        s += strip_sums[(size_t)63 * TWOB + r];
    }
#pragma unroll
    for (int t = 64; t < 80; ++t) s += strip_sums[(size_t)t * TWOB + r];
    float local = logf(s) - pos[r];
#pragma unroll
    for (int off = 32; off >= 1; off >>= 1) local += __shfl_xor(local, off);
    if ((tid & 63) == 0) wsums[tid >> 6] = local;
    __syncthreads();
    if (tid == 0) {
        float bsum = wsums[0] + wsums[1] + wsums[2] + wsums[3];
        atomicAdd(loss_acc, bsum);
        __threadfence();                              // order loss add before counter add
        unsigned int done = atomicAdd(counter, 1u);
        if (done == gridDim.x - 1) {
            float total = atomicAdd(loss_acc, 0.0f);  // device-scope atomic read
            out[0] = total / (float)TWOB;
        }
    }
}

extern "C" void kernel_launch(void* const* d_in, const int* in_sizes, int n_in,
                              void* d_out, int out_size, void* d_ws, size_t ws_size,
                              hipStream_t stream) {
    const float* zi = (const float*)d_in[0];
    const float* zj = (const float*)d_in[1];
    // ws layout: zn (4 MB) | pos (32 KB) | strip_sums (80 slots x 32 KB = 2.56 MB) | loss_acc | counter
    unsigned short* zn = (unsigned short*)d_ws;
    float* pos        = (float*)((char*)d_ws + (size_t)TWOB * DIM * 2);
    float* strip_sums = pos + TWOB;
    float* loss_acc   = strip_sums + (size_t)NSLOT * TWOB;
    unsigned int* counter = (unsigned int*)(loss_acc + 1);
    float* out = (float*)d_out;

    normalize_k<<<dim3(TWOB / 4), 256, 0, stream>>>(zi, zj, zn, loss_acc, counter);
    ntxent_main<<<dim3(64, NQ), 256, 0, stream>>>(zn, pos, strip_sums);
    finalize_k<<<dim3(TWOB / 256), 256, 0, stream>>>(strip_sums, pos, loss_acc, counter, out);
}

// Round 12
// 97.779 us; speedup vs baseline: 1.0150x; 1.0150x over previous
//
#include <hip/hip_runtime.h>
#include <hip/hip_bf16.h>

#define B_ROWS 4096
#define TWOB   8192
#define DIM    256
#define INV_T  14.285714285714286f  // 1/0.07

#define BM 128
#define BN 128
#define NQ 8              // col-chunk blocks per row tile
// strip_sums sub-slots (one producer wave each -> plain stores, no atomics/zero-init):
//   0..63  : col-sum slot (jdist-1)*2 + wr, jdist = 1..32
//   64..79 : row-sum slot 64 + q*2 + wc
#define NSLOT 80

typedef __bf16 bf16x8 __attribute__((ext_vector_type(8)));
typedef float  f32x4  __attribute__((ext_vector_type(4)));

// ---------------- kernel 1: row L2-normalize, fp32 -> bf16 ----------------
// Also zeroes the finalize accumulators (ws is re-poisoned 0xAA before every launch).
__global__ __launch_bounds__(256) void normalize_k(const float* __restrict__ zi,
                                                   const float* __restrict__ zj,
                                                   unsigned short* __restrict__ zn,
                                                   float* __restrict__ loss_acc,
                                                   unsigned int* __restrict__ counter) {
    if (blockIdx.x == 0 && threadIdx.x == 0) {
        loss_acc[0] = 0.0f;
        counter[0]  = 0u;
    }
    int wave = threadIdx.x >> 6;
    int lane = threadIdx.x & 63;
    int row  = blockIdx.x * 4 + wave;             // 2048 blocks * 4 waves = 8192 rows
    const float* src = (row < B_ROWS) ? (zi + (size_t)row * DIM)
                                      : (zj + (size_t)(row - B_ROWS) * DIM);
    float4 v = reinterpret_cast<const float4*>(src)[lane];   // 64 lanes * 4 = 256
    float ss = v.x * v.x + v.y * v.y + v.z * v.z + v.w * v.w;
#pragma unroll
    for (int off = 32; off >= 1; off >>= 1) ss += __shfl_xor(ss, off);
    float norm = sqrtf(ss);
    norm = fmaxf(norm, 1e-8f);                    // COS_EPS
    float inv = 1.0f / norm;
    ushort4 o;
    o.x = __builtin_bit_cast(unsigned short, __float2bfloat16(v.x * inv));
    o.y = __builtin_bit_cast(unsigned short, __float2bfloat16(v.y * inv));
    o.z = __builtin_bit_cast(unsigned short, __float2bfloat16(v.z * inv));
    o.w = __builtin_bit_cast(unsigned short, __float2bfloat16(v.w * inv));
    reinterpret_cast<ushort4*>(zn)[(size_t)row * 64 + lane] = o;
}

// ---------------- kernel 2: symmetric flash NT-Xent main ----------------
// sim = zn@zn^T is SYMMETRIC: each off-diagonal tile (r,c) supplies row sums for
// rows of r (rsum regs) AND, via its col sums, row sums for rows of c. Upper band
// only: block (rt,q) handles col tiles c=(rt+j)&63, j in {4q..4q+3}; additionally
// the j=32 diagonal-pair tile of row rt (rt<32) is assigned to chunk q == (rt&7)
// -> 2080 of 4096 tiles. R12 change vs R9: heavy 5-tile blocks were all (rt<32,
// q=7) — consecutive dispatch indices -> pairwise co-location on CUs -> 10-unit
// makespan vs 8.1 avg. Spreading them across q slices (4 per y-slice, 64 apart)
// removes the heavy-heavy pairing tail. Sub-slot scheme unchanged (row-sum slot
// is q-keyed per block; j=32 col slots 62/63 still unique-producer).
// Compute loop = R0/R9's verified structure (A LDS-resident staged once, B
// ping-pong staged one kstep ahead, 80 KB LDS -> 2 blocks/CU).
__global__ __launch_bounds__(256, 2) void ntxent_main(const unsigned short* __restrict__ znu,
                                                      float* __restrict__ pos,
                                                      float* __restrict__ strip_sums) {
    const __bf16* zn = (const __bf16*)znu;
    __shared__ __attribute__((aligned(16))) __bf16 As[8][BM * 32];   // 8 kt-chunks x 8 KB = 64 KB
    __shared__ __attribute__((aligned(16))) __bf16 Bs[2][BN * 32];   // ping-pong, 16 KB

    const int tid  = threadIdx.x;
    const int wave = tid >> 6;
    const int lane = tid & 63;
    const int wr = wave >> 1, wc = wave & 1;
    const int quad = lane >> 4, lc = lane & 15;
    const int rt = blockIdx.x;           // row-tile 0..63
    const int q  = blockIdx.y;           // col-chunk 0..7
    const int q4 = q * 4;
    const int row0 = rt * BM;
    const int NCT = (rt < 32 && q == (rt & 7)) ? 5 : 4;   // spread heavy blocks across q
#define COLOF(i) ((rt + (((i) == 4) ? 32 : (q4 + (i)))) & 63)

    // staging: per-lane global element offsets for this wave's two 1KB chunks per stage.
    // chunk c = j*64+lane -> (m=c>>2, kc_lds=c&3); source kc_g = kc_lds ^ sw(m)  (involution)
    int stg_off[2];
#pragma unroll
    for (int t = 0; t < 2; ++t) {
        int c  = (wave * 2 + t) * 64 + lane;
        int m  = c >> 2;
        int kc = (c & 3) ^ ((m & 3) ^ ((m >> 2) & 3));
        stg_off[t] = m * DIM + kc * 8;
    }

    // fragment-read byte offsets within one 8KB chunk (swizzle depends only on m&15 == lc)
    const int sw    = (lc & 3) ^ ((lc >> 2) & 3);
    const int aBase = (wr * 64 + lc) * 64 + ((quad ^ sw) * 16);
    const int bBase = (wc * 64 + lc) * 64 + ((quad ^ sw) * 16);

    // ---- prologue: stage full A (8 chunks) + first B chunk ----
#pragma unroll
    for (int kt = 0; kt < 8; ++kt) {
#pragma unroll
        for (int t = 0; t < 2; ++t) {
            const int j = wave * 2 + t;
            const __bf16* ga = zn + row0 * DIM + kt * 32 + stg_off[t];
            __builtin_amdgcn_global_load_lds(
                (const __attribute__((address_space(1))) void*)ga,
                (__attribute__((address_space(3))) void*)((char*)As + kt * 8192 + j * 1024), 16, 0, 0);
        }
    }
    {
        const int col0 = COLOF(0) * BN;
#pragma unroll
        for (int t = 0; t < 2; ++t) {
            const int j = wave * 2 + t;
            const __bf16* gb = zn + col0 * DIM + stg_off[t];
            __builtin_amdgcn_global_load_lds(
                (const __attribute__((address_space(1))) void*)gb,
                (__attribute__((address_space(3))) void*)((char*)Bs + j * 1024), 16, 0, 0);
        }
    }

    f32x4 acc[4][4];
    float rsum[4][4];
    float posv[4] = {0.f, 0.f, 0.f, 0.f};
    int   posm[4] = {-1, -1, -1, -1};
#pragma unroll
    for (int mi = 0; mi < 4; ++mi)
#pragma unroll
        for (int r = 0; r < 4; ++r) rsum[mi][r] = 0.0f;

    for (int ct = 0; ct < NCT; ++ct) {
        const int jdist = (ct == 4) ? 32 : (q4 + ct);
        const int c     = (rt + jdist) & 63;
        const int col0  = c * BN;
#pragma unroll
        for (int mi = 0; mi < 4; ++mi)
#pragma unroll
            for (int ni = 0; ni < 4; ++ni) acc[mi][ni] = f32x4{0.f, 0.f, 0.f, 0.f};

#pragma unroll
        for (int kt = 0; kt < 8; ++kt) {
            // barrier: (a) drains the B stage issued one iteration ago (covered
            // by that iteration's compute), (b) guards reuse of Bs[kt+1 & 1].
            __syncthreads();

            // stage next B chunk into the other buffer
            {
                const int nct = (kt == 7) ? ct + 1 : ct;
                const int nkt = (kt + 1) & 7;
                if (nct < NCT) {
                    const int ncol0 = COLOF(nct) * BN;
#pragma unroll
                    for (int t = 0; t < 2; ++t) {
                        const int j = wave * 2 + t;
                        const __bf16* gb = zn + ncol0 * DIM + nkt * 32 + stg_off[t];
                        __builtin_amdgcn_global_load_lds(
                            (const __attribute__((address_space(1))) void*)gb,
                            (__attribute__((address_space(3))) void*)((char*)Bs + ((kt + 1) & 1) * 8192 + j * 1024),
                            16, 0, 0);
                    }
                }
            }

            bf16x8 af[4], bfr[4];
#pragma unroll
            for (int mi = 0; mi < 4; ++mi)
                af[mi] = *(const bf16x8*)((const char*)As + kt * 8192 + aBase + mi * 1024);
#pragma unroll
            for (int ni = 0; ni < 4; ++ni)
                bfr[ni] = *(const bf16x8*)((const char*)Bs + (kt & 1) * 8192 + bBase + ni * 1024);
#pragma unroll
            for (int mi = 0; mi < 4; ++mi)
#pragma unroll
                for (int ni = 0; ni < 4; ++ni)
                    acc[mi][ni] = __builtin_amdgcn_mfma_f32_16x16x32_bf16(
                        af[mi], bfr[ni], acc[mi][ni], 0, 0, 0);
        }

        // epilogue: exp + row sums (C/D layout: row = quad*4+reg, col = lc) + col sums.
        // Runs while the next tile's kt=0 B stage is in flight (no barriers here).
        const bool isDiag = (jdist == 0);
        const bool isPos  = (jdist == 32);
        float cadd[4] = {0.f, 0.f, 0.f, 0.f};
#pragma unroll
        for (int mi = 0; mi < 4; ++mi) {
#pragma unroll
            for (int ni = 0; ni < 4; ++ni) {
                f32x4 a = acc[mi][ni];
#pragma unroll
                for (int r = 0; r < 4; ++r) {
                    float logit = a[r] * INV_T;
                    float e = __expf(logit);
                    if (isDiag || isPos) {
                        int gr = row0 + wr * 64 + mi * 16 + quad * 4 + r;
                        int gc = col0 + wc * 64 + ni * 16 + lc;
                        if (isPos && gc == gr + B_ROWS) { posv[mi] = logit; posm[mi] = gr; }
                        if (isDiag && gr == gc) e = 0.0f;    // diagonal mask
                    }
                    rsum[mi][r] += e;
                    cadd[ni]    += e;
                }
            }
        }

        // col-sum flush: quad reduce (rows within wave) then DIRECT store to the
        // per-wave sub-slot (unique producer -> no atomics, no barrier, no LDS).
        if (!isDiag) {
#pragma unroll
            for (int ni = 0; ni < 4; ++ni) {
                cadd[ni] += __shfl_xor(cadd[ni], 16);   // sum over quad bit 0
                cadd[ni] += __shfl_xor(cadd[ni], 32);   // sum over quad bit 1
            }
            if (quad == 0) {
                float* dst = strip_sums + (size_t)((jdist - 1) * 2 + wr) * TWOB + col0 + wc * 64 + lc;
#pragma unroll
                for (int ni = 0; ni < 4; ++ni) dst[ni * 16] = cadd[ni];
            }
        }
    }

    // deferred pos stores: j==32 tiles hold both directions of each positive pair
#pragma unroll
    for (int mi = 0; mi < 4; ++mi)
        if (posm[mi] >= 0) {
            pos[posm[mi]] = posv[mi];
            pos[posm[mi] + B_ROWS] = posv[mi];
        }

    // row-sum flush: lane reduce over lc bits then DIRECT store to per-wave sub-slot.
    {
        float* rdst = strip_sums + (size_t)(64 + q * 2 + wc) * TWOB + row0 + wr * 64;
#pragma unroll
        for (int mi = 0; mi < 4; ++mi) {
#pragma unroll
            for (int r = 0; r < 4; ++r) {
                float v = rsum[mi][r];
                v += __shfl_xor(v, 1);
                v += __shfl_xor(v, 2);
                v += __shfl_xor(v, 4);
                v += __shfl_xor(v, 8);
                if (lc == 0) rdst[mi * 16 + quad * 4 + r] = v;
            }
        }
    }
}

// ---------------- kernel 3: loss = mean(log(sumexp) - pos) ----------------
// Row r coverage: col sub-slots 0..61 (j=1..31, both wr) for all rows; 62,63
// (j=32) only for rows >= 4096 (rows < 4096 get distance-32 via row-sum path);
// row sub-slots 64..79. Exactly the 64 tile-distances once each.
__global__ __launch_bounds__(256) void finalize_k(const float* __restrict__ strip_sums,
                                                  const float* __restrict__ pos,
                                                  float* __restrict__ loss_acc,
                                                  unsigned int* __restrict__ counter,
                                                  float* __restrict__ out) {
    __shared__ float wsums[4];
    const int tid = threadIdx.x;
    const int r   = blockIdx.x * 256 + tid;
    float s = 0.0f;
#pragma unroll
    for (int t = 0; t < 62; ++t) s += strip_sums[(size_t)t * TWOB + r];
    if (r >= B_ROWS) {
        s += strip_sums[(size_t)62 * TWOB + r];
        s += strip_sums[(size_t)63 * TWOB + r];
    }
#pragma unroll
    for (int t = 64; t < 80; ++t) s += strip_sums[(size_t)t * TWOB + r];
    float local = logf(s) - pos[r];
#pragma unroll
    for (int off = 32; off >= 1; off >>= 1) local += __shfl_xor(local, off);
    if ((tid & 63) == 0) wsums[tid >> 6] = local;
    __syncthreads();
    if (tid == 0) {
        float bsum = wsums[0] + wsums[1] + wsums[2] + wsums[3];
        atomicAdd(loss_acc, bsum);
        __threadfence();                              // order loss add before counter add
        unsigned int done = atomicAdd(counter, 1u);
        if (done == gridDim.x - 1) {
            float total = atomicAdd(loss_acc, 0.0f);  // device-scope atomic read
            out[0] = total / (float)TWOB;
        }
    }
}

extern "C" void kernel_launch(void* const* d_in, const int* in_sizes, int n_in,
                              void* d_out, int out_size, void* d_ws, size_t ws_size,
                              hipStream_t stream) {
    const float* zi = (const float*)d_in[0];
    const float* zj = (const float*)d_in[1];
    // ws layout: zn (4 MB) | pos (32 KB) | strip_sums (80 slots x 32 KB = 2.56 MB) | loss_acc | counter
    unsigned short* zn = (unsigned short*)d_ws;
    float* pos        = (float*)((char*)d_ws + (size_t)TWOB * DIM * 2);
    float* strip_sums = pos + TWOB;
    float* loss_acc   = strip_sums + (size_t)NSLOT * TWOB;
    unsigned int* counter = (unsigned int*)(loss_acc + 1);
    float* out = (float*)d_out;

    normalize_k<<<dim3(TWOB / 4), 256, 0, stream>>>(zi, zj, zn, loss_acc, counter);
    ntxent_main<<<dim3(64, NQ), 256, 0, stream>>>(zn, pos, strip_sums);
    finalize_k<<<dim3(TWOB / 256), 256, 0, stream>>>(strip_sums, pos, loss_acc, counter, out);
}